// Round 9
// baseline (573.093 us; speedup 1.0000x reference)
//
#include <hip/hip_runtime.h>
#include <hip/hip_fp16.h>
#include <math.h>

#define BKT_SHIFT 6
#define BKT_NODES 64
#define HROWS 64

// ---- pass 1: per-bucket histogram ----
__global__ __launch_bounds__(256) void k_hist(const int* __restrict__ dst,
                                              int* __restrict__ bcnt, int E, int NB) {
    __shared__ int lh[2048];
    for (int i = threadIdx.x; i < NB; i += 256) lh[i] = 0;
    __syncthreads();
    int base = blockIdx.x * 4096;
    if (base + 4096 <= E) {
        const int4* d4 = (const int4*)(dst + base);
#pragma unroll
        for (int k = 0; k < 4; ++k) {
            int4 v = d4[k * 256 + threadIdx.x];
            atomicAdd(&lh[v.x >> BKT_SHIFT], 1);
            atomicAdd(&lh[v.y >> BKT_SHIFT], 1);
            atomicAdd(&lh[v.z >> BKT_SHIFT], 1);
            atomicAdd(&lh[v.w >> BKT_SHIFT], 1);
        }
    } else {
        for (int k = 0; k < 16; ++k) {
            int i = base + k * 256 + threadIdx.x;
            if (i < E) atomicAdd(&lh[dst[i] >> BKT_SHIFT], 1);
        }
    }
    __syncthreads();
    for (int i = threadIdx.x; i < NB; i += 256)
        if (lh[i]) atomicAdd(&bcnt[i], lh[i]);
}

// ---- exclusive scan over NB buckets (single block) ----
__global__ __launch_bounds__(512) void k_bscan(const int* __restrict__ bc,
                                               int* __restrict__ boff,
                                               int* __restrict__ bcur, int NB, int E) {
    __shared__ int s[512];
    __shared__ int carry;
    if (threadIdx.x == 0) carry = 0;
    __syncthreads();
    for (int base = 0; base < NB; base += 512) {
        int i = base + threadIdx.x;
        int v = (i < NB) ? bc[i] : 0;
        s[threadIdx.x] = v;
        __syncthreads();
        for (int off = 1; off < 512; off <<= 1) {
            int t = (threadIdx.x >= off) ? s[threadIdx.x - off] : 0;
            __syncthreads();
            s[threadIdx.x] += t;
            __syncthreads();
        }
        if (i < NB) {
            int ex = carry + s[threadIdx.x] - v;
            boff[i] = ex;
            bcur[i] = ex;
        }
        __syncthreads();
        if (threadIdx.x == 0) carry += s[511];
        __syncthreads();
    }
    if (threadIdx.x == 0) boff[NB] = E;
}

// ---- pass 2: partition edges; record = (d&63)<<24 | src ----
__global__ __launch_bounds__(256) void k_part(const int* __restrict__ src,
                                              const int* __restrict__ dst,
                                              int* __restrict__ bcur,
                                              int* __restrict__ ebuf, int E, int NB) {
    __shared__ int dstash[8192];
    __shared__ int lh[2048];
    for (int i = threadIdx.x; i < NB; i += 256) lh[i] = 0;
    __syncthreads();
    int base = blockIdx.x * 8192;
    if (base + 8192 <= E) {
        const int4* d4 = (const int4*)(dst + base);
#pragma unroll
        for (int k = 0; k < 8; ++k) {
            int i4 = k * 256 + threadIdx.x;
            int4 v = d4[i4];
            *(int4*)&dstash[i4 * 4] = v;
            atomicAdd(&lh[v.x >> BKT_SHIFT], 1);
            atomicAdd(&lh[v.y >> BKT_SHIFT], 1);
            atomicAdd(&lh[v.z >> BKT_SHIFT], 1);
            atomicAdd(&lh[v.w >> BKT_SHIFT], 1);
        }
    } else {
        for (int k = 0; k < 32; ++k) {
            int idx = k * 256 + threadIdx.x;
            int i = base + idx;
            if (i < E) {
                int d = dst[i];
                dstash[idx] = d;
                atomicAdd(&lh[d >> BKT_SHIFT], 1);
            }
        }
    }
    __syncthreads();
    for (int t = threadIdx.x; t < NB; t += 256) {
        int c = lh[t];
        lh[t] = c ? atomicAdd(&bcur[t], c) : 0;
    }
    __syncthreads();
#pragma unroll
    for (int k = 0; k < 32; ++k) {
        int idx = k * 256 + threadIdx.x;
        int i = base + idx;
        if (i < E) {
            int d = dstash[idx];
            int pos = atomicAdd(&lh[d >> BKT_SHIFT], 1);
            ebuf[pos] = ((d & (BKT_NODES - 1)) << 24) | src[i];
        }
    }
}

// ---- pass 3: per-bucket (64-node) counting sort -> csr (full rec), rowstart, dinv ----
__global__ __launch_bounds__(256) void k_lsort(const int* __restrict__ boff,
                                               const int* __restrict__ ebuf,
                                               int* __restrict__ rowstart,
                                               float* __restrict__ dinv,
                                               int* __restrict__ csr, int n, int NB) {
    __shared__ int cnt[64];
    __shared__ int cur[64];
    int b = blockIdx.x;
    int start = boff[b], end = boff[b + 1];
    if (threadIdx.x < 64) cnt[threadIdx.x] = 0;
    __syncthreads();
    for (int i = start + threadIdx.x; i < end; i += 256)
        atomicAdd(&cnt[((unsigned)__builtin_nontemporal_load(ebuf + i)) >> 24], 1);
    __syncthreads();
    if (threadIdx.x < 64) {
        int v = cnt[threadIdx.x];
        int inc = v;
#pragma unroll
        for (int d = 1; d < 64; d <<= 1) {
            int t = __shfl_up(inc, d);
            if ((int)(threadIdx.x) >= d) inc += t;
        }
        int excl = inc - v;
        cur[threadIdx.x] = excl;
        int node = b * BKT_NODES + threadIdx.x;
        if (node < n) {
            rowstart[node] = start + excl;
            dinv[node] = rsqrtf((float)v + 1.0f);  // +1 = self-loop
        }
    }
    __syncthreads();
    for (int i = start + threadIdx.x; i < end; i += 256) {
        int rec = __builtin_nontemporal_load(ebuf + i);
        int pos = atomicAdd(&cur[((unsigned)rec) >> 24], 1);
        csr[start + pos] = rec;   // keep d in high byte
    }
    if (b == NB - 1 && threadIdx.x == 0) rowstart[n] = end;
}

// ---- hx = fp16(x * dinv), [N][8] ----
__global__ __launch_bounds__(256) void k_hx(const float* __restrict__ x,
                                            const float* __restrict__ dinv,
                                            __half2* __restrict__ hx, int n4) {
    int t = blockIdx.x * 256 + threadIdx.x;
    if (t >= n4) return;
    float2 v = ((const float2*)x)[t];
    float dv = dinv[t >> 2];
    hx[t] = __floats2half2_rn(v.x * dv, v.y * dv);
}

// ---- fused layer-1: aggregate hx (8 feats) then @W1+bias+ELU ----
__global__ __launch_bounds__(256) void k_agg1f(const int* __restrict__ rs, const int* __restrict__ csr,
                                               const float* __restrict__ dinv, const __half2* __restrict__ hx,
                                               const float* __restrict__ W1, const float* __restrict__ bias,
                                               float* __restrict__ g, int n) {
    __shared__ float w[512];
    for (int i = threadIdx.x; i < 512; i += 256) w[i] = W1[i];
    __syncthreads();
    int wid = (blockIdx.x * 256 + threadIdx.x) >> 6;
    if (wid >= n) return;
    int lane = threadIdx.x & 63;
    int sub = lane >> 2;        // 0..15 edge subset
    int jp = lane & 3;          // half2 index
    int start = rs[wid], end = rs[wid + 1];
    float ax = 0.f, ay = 0.f;
    int i = start + sub;
    for (; i + 16 < end; i += 32) {
        int s0 = __builtin_nontemporal_load(csr + i) & 0xFFFFFF;
        int s1 = __builtin_nontemporal_load(csr + i + 16) & 0xFFFFFF;
        float2 f0 = __half22float2(hx[((size_t)s0 << 2) + jp]);
        float2 f1 = __half22float2(hx[((size_t)s1 << 2) + jp]);
        ax += f0.x + f1.x;
        ay += f0.y + f1.y;
    }
    for (; i < end; i += 16) {
        int s = __builtin_nontemporal_load(csr + i) & 0xFFFFFF;
        float2 f = __half22float2(hx[((size_t)s << 2) + jp]);
        ax += f.x; ay += f.y;
    }
    if (sub == 0) {
        float2 f = __half22float2(hx[((size_t)wid << 2) + jp]);
        ax += f.x; ay += f.y;
    }
#pragma unroll
    for (int m = 4; m < 64; m <<= 1) {
        ax += __shfl_xor(ax, m);
        ay += __shfl_xor(ay, m);
    }
    float dv = dinv[wid];
    float s = 0.f;
#pragma unroll
    for (int kp = 0; kp < 4; ++kp) {
        float a = __shfl(ax, kp);
        float b = __shfl(ay, kp);
        s += a * w[(2 * kp) * 64 + lane] + b * w[(2 * kp + 1) * 64 + lane];
    }
    float v = dv * s + bias[lane];
    v = v > 0.f ? v : expm1f(v);
    __builtin_nontemporal_store(v, g + (size_t)wid * 64 + lane);
}

// ---- layer-2 variant A: wave-per-node, 32 feats, nodes [0, nA) ----
__global__ __launch_bounds__(256) void k_agg2A(const int* __restrict__ rs, const int* __restrict__ csr,
                                               const float* __restrict__ dinv, const __half* __restrict__ hw,
                                               const float* __restrict__ bias, float* __restrict__ g, int nA) {
    int wid = (blockIdx.x * 256 + threadIdx.x) >> 6;
    if (wid >= nA) return;
    int lane = threadIdx.x & 63;
    int q = lane >> 4;
    int j = lane & 15;
    int start = rs[wid], end = rs[wid + 1];
    const __half2* hp = (const __half2*)hw;
    float ax = 0.f, ay = 0.f;
    int i = start + q;
    for (; i + 12 < end; i += 16) {
        int s0 = __builtin_nontemporal_load(csr + i) & 0xFFFFFF;
        int s1 = __builtin_nontemporal_load(csr + i + 4) & 0xFFFFFF;
        int s2 = __builtin_nontemporal_load(csr + i + 8) & 0xFFFFFF;
        int s3 = __builtin_nontemporal_load(csr + i + 12) & 0xFFFFFF;
        float2 f0 = __half22float2(hp[((size_t)s0 << 4) + j]);
        float2 f1 = __half22float2(hp[((size_t)s1 << 4) + j]);
        float2 f2 = __half22float2(hp[((size_t)s2 << 4) + j]);
        float2 f3 = __half22float2(hp[((size_t)s3 << 4) + j]);
        ax += f0.x + f1.x + f2.x + f3.x;
        ay += f0.y + f1.y + f2.y + f3.y;
    }
    for (; i < end; i += 4) {
        int s = __builtin_nontemporal_load(csr + i) & 0xFFFFFF;
        float2 f = __half22float2(hp[((size_t)s << 4) + j]);
        ax += f.x; ay += f.y;
    }
    ax += __shfl_xor(ax, 16);
    ay += __shfl_xor(ay, 16);
    ax += __shfl_xor(ax, 32);
    ay += __shfl_xor(ay, 32);
    if (q == 0) {
        float dv = dinv[wid];
        float2 fs = __half22float2(hp[((size_t)wid << 4) + j]);
        float2 bb = ((const float2*)bias)[j];
        float vx = dv * (ax + fs.x) + bb.x;
        float vy = dv * (ay + fs.y) + bb.y;
        float2 r;
        r.x = vx > 0.f ? vx : expm1f(vx);
        r.y = vy > 0.f ? vy : expm1f(vy);
        ((float2*)(g + ((size_t)wid << 5)))[j] = r;
    }
}

// ---- layer-2 variant C: edge-parallel LDS accumulation, one block per bucket >= NBh ----
__global__ __launch_bounds__(512) void k_agg2C(const int* __restrict__ boff, const int* __restrict__ ebuf,
                                               const float* __restrict__ dinv, const __half* __restrict__ hw,
                                               const float* __restrict__ bias, float* __restrict__ g,
                                               int n, int bucket0) {
    __shared__ float acc[BKT_NODES * 33];   // +1 pad: 8.4 KB
    for (int i = threadIdx.x; i < BKT_NODES * 33; i += 512) acc[i] = 0.f;
    int b = bucket0 + blockIdx.x;
    int start = boff[b], end = boff[b + 1];
    __syncthreads();
    int jl = threadIdx.x & 7;        // 8B feature lane (feats 4jl..4jl+3)
    int eo = threadIdx.x >> 3;       // edge slot 0..63
    const uint2* hp = (const uint2*)hw;   // 8B units; row = 8 units
    for (int i = start + eo; i < end; i += 64) {
        int rec = __builtin_nontemporal_load(ebuf + i);
        int src = rec & 0xFFFFFF;
        int ld = ((unsigned)rec) >> 24;
        uint2 rv = hp[((size_t)src << 3) + jl];
        float2 f0 = __half22float2(*(__half2*)&rv.x);
        float2 f1 = __half22float2(*(__half2*)&rv.y);
        int abase = ld * 33 + jl * 4;
        atomicAdd(&acc[abase + 0], f0.x);
        atomicAdd(&acc[abase + 1], f0.y);
        atomicAdd(&acc[abase + 2], f1.x);
        atomicAdd(&acc[abase + 3], f1.y);
    }
    __syncthreads();
    int nbase = b * BKT_NODES;
    for (int idx = threadIdx.x; idx < BKT_NODES * 32; idx += 512) {
        int r = idx >> 5, f = idx & 31;
        int node = nbase + r;
        if (node < n) {
            float dv = dinv[node];
            float selfv = __half2float(hw[(size_t)node * 32 + f]);
            float v = dv * (acc[r * 33 + f] + selfv) + bias[f];
            g[(size_t)node * 32 + f] = v > 0.f ? v : expm1f(v);
        }
    }
}

// ---- hw2 = fp16((g1 @ W2) * dinv)  (64 -> 32), single plane ----
__global__ __launch_bounds__(256) void k_gemm2(const float* __restrict__ g1, const float* __restrict__ W2,
                                               const float* __restrict__ dinv, __half* __restrict__ hw2, int n) {
    __shared__ float w[2048];
    __shared__ float xs[512];
    for (int i = threadIdx.x; i < 2048; i += 256) w[i] = W2[i];
    int nb = blockIdx.x * 8;
    for (int i = threadIdx.x; i < 512; i += 256) {
        int r = i >> 6, c = i & 63;
        int node = nb + r;
        xs[i] = (node < n) ? __builtin_nontemporal_load(g1 + (size_t)node * 64 + c) : 0.f;
    }
    __syncthreads();
    int node = nb + (threadIdx.x >> 5);
    int j = threadIdx.x & 31;
    if (node >= n) return;
    const float* xr = &xs[(threadIdx.x >> 5) << 6];
    float s = 0.f;
#pragma unroll
    for (int k = 0; k < 64; ++k) s += xr[k] * w[k * 32 + j];
    hw2[(size_t)node * 32 + j] = __float2half_rn(s * dinv[node]);
}

// ---- cooperative head: conv1d(32->16,k=3)+relu+fc(16->22), 64 rows/block ----
__global__ __launch_bounds__(256) void k_head(const float* __restrict__ g2, const float* __restrict__ cw,
                                              const float* __restrict__ cb, const float* __restrict__ fw,
                                              const float* __restrict__ fb, float* __restrict__ out,
                                              int nrows) {
    __shared__ float tile[(HROWS + 2) * 36];
    __shared__ float scwT[96 * 16];
    __shared__ float ytile[HROWS * 20];
    __shared__ float sfwT[22 * 16];
    __shared__ float scb[16], sfb[22];
    int base = blockIdx.x * HROWS;
    int rcnt = nrows - base; if (rcnt > HROWS) rcnt = HROWS;
    for (int i = threadIdx.x; i < 1536; i += 256) {
        int co = i / 96, rem = i - co * 96;
        scwT[rem * 16 + co] = cw[i];
    }
    for (int i = threadIdx.x; i < 352; i += 256) {
        int co = i / 22, col = i - co * 22;
        sfwT[col * 16 + co] = fw[i];
    }
    if (threadIdx.x < 16) scb[threadIdx.x] = cb[threadIdx.x];
    if (threadIdx.x < 22) sfb[threadIdx.x] = fb[threadIdx.x];
    int nload4 = (rcnt + 2) * 8;
    for (int i = threadIdx.x; i < nload4; i += 256) {
        int r = i >> 3, c4 = i & 7;
        float4 v = *(const float4*)(g2 + (size_t)(base + r) * 32 + c4 * 4);
        *(float4*)&tile[r * 36 + c4 * 4] = v;
    }
    __syncthreads();
    int r = threadIdx.x >> 2;
    int c0 = threadIdx.x & 3;
    if (r < rcnt) {
        float4 acc = { scb[c0 * 4], scb[c0 * 4 + 1], scb[c0 * 4 + 2], scb[c0 * 4 + 3] };
#pragma unroll
        for (int k = 0; k < 3; ++k) {
            const float* tr = &tile[(r + k) * 36];
#pragma unroll
            for (int ci4 = 0; ci4 < 8; ++ci4) {
                float4 xv = *(const float4*)&tr[ci4 * 4];
#pragma unroll
                for (int q = 0; q < 4; ++q) {
                    int ci = ci4 * 4 + q;
                    float4 wv = *(const float4*)&scwT[(ci * 3 + k) * 16 + c0 * 4];
                    float xq = q == 0 ? xv.x : q == 1 ? xv.y : q == 2 ? xv.z : xv.w;
                    acc.x += xq * wv.x;
                    acc.y += xq * wv.y;
                    acc.z += xq * wv.z;
                    acc.w += xq * wv.w;
                }
            }
        }
        float4 yv;
        yv.x = acc.x > 0.f ? acc.x : 0.f;
        yv.y = acc.y > 0.f ? acc.y : 0.f;
        yv.z = acc.z > 0.f ? acc.z : 0.f;
        yv.w = acc.w > 0.f ? acc.w : 0.f;
        *(float4*)&ytile[r * 20 + c0 * 4] = yv;
    }
    __syncthreads();
    int items = rcnt * 22;
    for (int it = threadIdx.x; it < items; it += 256) {
        int row = it / 22, col = it - row * 22;
        const float* yr = &ytile[row * 20];
        const float* wc = &sfwT[col * 16];
        float s = sfb[col];
#pragma unroll
        for (int co4 = 0; co4 < 4; ++co4) {
            float4 yv = *(const float4*)&yr[co4 * 4];
            float4 wv = *(const float4*)&wc[co4 * 4];
            s += yv.x * wv.x + yv.y * wv.y + yv.z * wv.z + yv.w * wv.w;
        }
        out[(size_t)base * 22 + it] = s;
    }
}

extern "C" void kernel_launch(void* const* d_in, const int* in_sizes, int n_in,
                              void* d_out, int out_size, void* d_ws, size_t ws_size,
                              hipStream_t stream) {
    const float* x  = (const float*)d_in[0];
    const int*   ei = (const int*)d_in[1];   // int32 (JAX x64 disabled)
    const float* W1 = (const float*)d_in[2];
    const float* b1 = (const float*)d_in[3];
    const float* W2 = (const float*)d_in[4];
    const float* b2 = (const float*)d_in[5];
    const float* cw = (const float*)d_in[6];
    const float* cb = (const float*)d_in[7];
    const float* fw = (const float*)d_in[8];
    const float* fb = (const float*)d_in[9];
    float* out = (float*)d_out;

    int N = in_sizes[0] / 8;       // 100000
    int E = in_sizes[1] / 2;       // 3200000
    const int* src = ei;
    const int* dst = ei + E;
    int NB = (N + BKT_NODES - 1) >> BKT_SHIFT;  // 1563
    int NBh = NB / 2;                            // 781  (A/B split point)
    int nA = NBh * BKT_NODES;                    // nodes handled by variant A

    auto alignB = [](size_t v) { return (v + 1023) & ~(size_t)1023; };
    char* wsb = (char*)d_ws;
    size_t o = 0;
    int* bcnt = (int*)(wsb + o);      o += 8192;
    int* boff = (int*)(wsb + o);      o += 8192;
    int* bcur = (int*)(wsb + o);      o += 8192;
    int* rowstart = (int*)(wsb + o);  o += alignB((size_t)(N + 1) * 4);
    float* dinv = (float*)(wsb + o);  o += alignB((size_t)N * 4);
    int* csr = (int*)(wsb + o);       o += alignB((size_t)E * 4);
    int* ebuf = (int*)(wsb + o);      o += alignB((size_t)E * 4);   // persistent (C uses it)
    __half2* hx = (__half2*)(wsb + o);  o += alignB((size_t)N * 8 * 2);
    __half* hw2 = (__half*)(wsb + o);   o += alignB((size_t)N * 32 * 2);
    float* B = (float*)(wsb + o);     o += (size_t)N * 64 * 4;      // g1, then g2

    hipMemsetAsync(bcnt, 0, (size_t)NB * sizeof(int), stream);
    k_hist<<<(E + 4095) / 4096, 256, 0, stream>>>(dst, bcnt, E, NB);
    k_bscan<<<1, 512, 0, stream>>>(bcnt, boff, bcur, NB, E);
    k_part<<<(E + 8191) / 8192, 256, 0, stream>>>(src, dst, bcur, ebuf, E, NB);
    k_lsort<<<NB, 256, 0, stream>>>(boff, ebuf, rowstart, dinv, csr, N, NB);

    k_hx<<<(N * 4 + 255) / 256, 256, 0, stream>>>(x, dinv, hx, N * 4);
    k_agg1f<<<(int)(((size_t)N * 64 + 255) / 256), 256, 0, stream>>>(rowstart, csr, dinv, hx, W1, b1, B, N);

    k_gemm2<<<(N + 7) / 8, 256, 0, stream>>>(B, W2, dinv, hw2, N);
    // layer-2 A/B: variant A on first half of nodes, variant C on second half
    k_agg2A<<<(int)(((size_t)nA * 64 + 255) / 256), 256, 0, stream>>>(rowstart, csr, dinv, hw2, b2, B, nA);
    k_agg2C<<<NB - NBh, 512, 0, stream>>>(boff, ebuf, dinv, hw2, b2, B, N, NBh);

    k_head<<<(N - 2 + HROWS - 1) / HROWS, 256, 0, stream>>>(B, cw, cb, fw, fb, out, N - 2);
}

// Round 10
// 261.496 us; speedup vs baseline: 2.1916x; 2.1916x over previous
//
#include <hip/hip_runtime.h>
#include <hip/hip_fp16.h>
#include <math.h>

#define BKT_SHIFT 8
#define BKT_NODES 256
#define HROWS 64

// ---- pass 1: per-bucket histogram (int4-vectorized dst read) ----
__global__ __launch_bounds__(256) void k_hist(const int* __restrict__ dst,
                                              int* __restrict__ bcnt, int E, int NB) {
    __shared__ int lh[512];
    for (int i = threadIdx.x; i < NB; i += 256) lh[i] = 0;
    __syncthreads();
    int base = blockIdx.x * 4096;
    if (base + 4096 <= E) {
        const int4* d4 = (const int4*)(dst + base);
#pragma unroll
        for (int k = 0; k < 4; ++k) {
            int4 v = d4[k * 256 + threadIdx.x];
            atomicAdd(&lh[v.x >> BKT_SHIFT], 1);
            atomicAdd(&lh[v.y >> BKT_SHIFT], 1);
            atomicAdd(&lh[v.z >> BKT_SHIFT], 1);
            atomicAdd(&lh[v.w >> BKT_SHIFT], 1);
        }
    } else {
        for (int k = 0; k < 16; ++k) {
            int i = base + k * 256 + threadIdx.x;
            if (i < E) atomicAdd(&lh[dst[i] >> BKT_SHIFT], 1);
        }
    }
    __syncthreads();
    for (int i = threadIdx.x; i < NB; i += 256)
        if (lh[i]) atomicAdd(&bcnt[i], lh[i]);
}

// ---- exclusive scan over NB buckets (single block) ----
__global__ __launch_bounds__(512) void k_bscan(const int* __restrict__ bc,
                                               int* __restrict__ boff,
                                               int* __restrict__ bcur, int NB, int E) {
    __shared__ int s[512];
    __shared__ int carry;
    if (threadIdx.x == 0) carry = 0;
    __syncthreads();
    for (int base = 0; base < NB; base += 512) {
        int i = base + threadIdx.x;
        int v = (i < NB) ? bc[i] : 0;
        s[threadIdx.x] = v;
        __syncthreads();
        for (int off = 1; off < 512; off <<= 1) {
            int t = (threadIdx.x >= off) ? s[threadIdx.x - off] : 0;
            __syncthreads();
            s[threadIdx.x] += t;
            __syncthreads();
        }
        if (i < NB) {
            int ex = carry + s[threadIdx.x] - v;
            boff[i] = ex;
            bcur[i] = ex;
        }
        __syncthreads();
        if (threadIdx.x == 0) carry += s[511];
        __syncthreads();
    }
    if (threadIdx.x == 0) boff[NB] = E;
}

// ---- pass 2: partition edges; record = (d&255)<<24 | src ----
__global__ __launch_bounds__(256) void k_part(const int* __restrict__ src,
                                              const int* __restrict__ dst,
                                              int* __restrict__ bcur,
                                              int* __restrict__ ebuf, int E, int NB) {
    __shared__ int dstash[8192];
    __shared__ int lh[512];
    for (int i = threadIdx.x; i < NB; i += 256) lh[i] = 0;
    __syncthreads();
    int base = blockIdx.x * 8192;
    if (base + 8192 <= E) {
        const int4* d4 = (const int4*)(dst + base);
#pragma unroll
        for (int k = 0; k < 8; ++k) {
            int i4 = k * 256 + threadIdx.x;
            int4 v = d4[i4];
            *(int4*)&dstash[i4 * 4] = v;
            atomicAdd(&lh[v.x >> BKT_SHIFT], 1);
            atomicAdd(&lh[v.y >> BKT_SHIFT], 1);
            atomicAdd(&lh[v.z >> BKT_SHIFT], 1);
            atomicAdd(&lh[v.w >> BKT_SHIFT], 1);
        }
    } else {
        for (int k = 0; k < 32; ++k) {
            int idx = k * 256 + threadIdx.x;
            int i = base + idx;
            if (i < E) {
                int d = dst[i];
                dstash[idx] = d;
                atomicAdd(&lh[d >> BKT_SHIFT], 1);
            }
        }
    }
    __syncthreads();
    for (int t = threadIdx.x; t < NB; t += 256) {
        int c = lh[t];
        lh[t] = c ? atomicAdd(&bcur[t], c) : 0;
    }
    __syncthreads();
#pragma unroll
    for (int k = 0; k < 32; ++k) {
        int idx = k * 256 + threadIdx.x;
        int i = base + idx;
        if (i < E) {
            int d = dstash[idx];
            int pos = atomicAdd(&lh[d >> BKT_SHIFT], 1);
            ebuf[pos] = ((d & (BKT_NODES - 1)) << 24) | src[i];
        }
    }
}

// ---- pass 3: per-bucket counting sort -> csr (masked src), rowstart, dinv ----
__global__ __launch_bounds__(256) void k_lsort(const int* __restrict__ boff,
                                               const int* __restrict__ ebuf,
                                               int* __restrict__ rowstart,
                                               float* __restrict__ dinv,
                                               int* __restrict__ csr, int n, int NB) {
    __shared__ int off[256];
    __shared__ int cnt[256];
    int b = blockIdx.x;
    int start = boff[b], end = boff[b + 1];
    cnt[threadIdx.x] = 0;
    __syncthreads();
    for (int i = start + threadIdx.x; i < end; i += 256)
        atomicAdd(&cnt[((unsigned)__builtin_nontemporal_load(ebuf + i)) >> 24], 1);
    __syncthreads();
    int v = cnt[threadIdx.x];
    off[threadIdx.x] = v;
    __syncthreads();
    for (int o = 1; o < 256; o <<= 1) {
        int t = (threadIdx.x >= o) ? off[threadIdx.x - o] : 0;
        __syncthreads();
        off[threadIdx.x] += t;
        __syncthreads();
    }
    int excl = off[threadIdx.x] - v;
    int node = (b << BKT_SHIFT) + threadIdx.x;
    if (node < n) {
        rowstart[node] = start + excl;
        dinv[node] = rsqrtf((float)v + 1.0f);  // +1 = self-loop
    }
    __syncthreads();
    off[threadIdx.x] = excl;  // reuse as cursor
    __syncthreads();
    for (int i = start + threadIdx.x; i < end; i += 256) {
        int rec = __builtin_nontemporal_load(ebuf + i);
        int d = ((unsigned)rec) >> 24;
        int pos = atomicAdd(&off[d], 1);
        csr[start + pos] = rec & 0xFFFFFF;
    }
    if (b == NB - 1 && threadIdx.x == 0) rowstart[n] = end;
}

// ---- hx = fp16(x * dinv), [N][8] ----
__global__ __launch_bounds__(256) void k_hx(const float* __restrict__ x,
                                            const float* __restrict__ dinv,
                                            __half2* __restrict__ hx, int n4) {
    int t = blockIdx.x * 256 + threadIdx.x;
    if (t >= n4) return;
    float2 v = ((const float2*)x)[t];
    float dv = dinv[t >> 2];
    hx[t] = __floats2half2_rn(v.x * dv, v.y * dv);
}

// ---- fused layer-1: 2 lanes x uint2 (4 feats) x 32 subsets, then @W1+bias+ELU ----
__global__ __launch_bounds__(256) void k_agg1v(const int* __restrict__ rs, const int* __restrict__ csr,
                                               const float* __restrict__ dinv, const uint2* __restrict__ hx,
                                               const float* __restrict__ W1, const float* __restrict__ bias,
                                               float* __restrict__ g, int n) {
    __shared__ float w[512];
    for (int i = threadIdx.x; i < 512; i += 256) w[i] = W1[i];
    __syncthreads();
    int wid = (blockIdx.x * 256 + threadIdx.x) >> 6;
    if (wid >= n) return;
    int lane = threadIdx.x & 63;
    int sub = lane >> 1;        // 0..31 edge subset
    int jl = lane & 1;          // uint2 index within 16B row
    int start = rs[wid], end = rs[wid + 1];
    float a0 = 0.f, a1 = 0.f, a2 = 0.f, a3 = 0.f;
    int i = start + sub;
    for (; i + 32 < end; i += 64) {
        int s0 = __builtin_nontemporal_load(csr + i);
        int s1 = __builtin_nontemporal_load(csr + i + 32);
        uint2 r0 = hx[((size_t)s0 << 1) + jl];
        uint2 r1 = hx[((size_t)s1 << 1) + jl];
        float2 p0 = __half22float2(*(__half2*)&r0.x);
        float2 p1 = __half22float2(*(__half2*)&r0.y);
        float2 q0 = __half22float2(*(__half2*)&r1.x);
        float2 q1 = __half22float2(*(__half2*)&r1.y);
        a0 += p0.x + q0.x; a1 += p0.y + q0.y;
        a2 += p1.x + q1.x; a3 += p1.y + q1.y;
    }
    for (; i < end; i += 32) {
        int s = __builtin_nontemporal_load(csr + i);
        uint2 r0 = hx[((size_t)s << 1) + jl];
        float2 p0 = __half22float2(*(__half2*)&r0.x);
        float2 p1 = __half22float2(*(__half2*)&r0.y);
        a0 += p0.x; a1 += p0.y; a2 += p1.x; a3 += p1.y;
    }
    if (sub == 0) {  // self-loop row
        uint2 r0 = hx[((size_t)wid << 1) + jl];
        float2 p0 = __half22float2(*(__half2*)&r0.x);
        float2 p1 = __half22float2(*(__half2*)&r0.y);
        a0 += p0.x; a1 += p0.y; a2 += p1.x; a3 += p1.y;
    }
#pragma unroll
    for (int m = 2; m < 64; m <<= 1) {
        a0 += __shfl_xor(a0, m);
        a1 += __shfl_xor(a1, m);
        a2 += __shfl_xor(a2, m);
        a3 += __shfl_xor(a3, m);
    }
    // lane jl=0 holds feats 0-3 sums, jl=1 holds feats 4-7 (lanes 0 and 1)
    float dv = dinv[wid];
    float s = __shfl(a0, 0) * w[0 * 64 + lane] + __shfl(a1, 0) * w[1 * 64 + lane]
            + __shfl(a2, 0) * w[2 * 64 + lane] + __shfl(a3, 0) * w[3 * 64 + lane]
            + __shfl(a0, 1) * w[4 * 64 + lane] + __shfl(a1, 1) * w[5 * 64 + lane]
            + __shfl(a2, 1) * w[6 * 64 + lane] + __shfl(a3, 1) * w[7 * 64 + lane];
    float v = dv * s + bias[lane];
    v = v > 0.f ? v : expm1f(v);
    __builtin_nontemporal_store(v, g + (size_t)wid * 64 + lane);
}

// ---- layer-2 aggregation: 8 lanes x uint2 (4 feats) x 8 subsets ----
__global__ __launch_bounds__(256) void k_aggr32v(const int* __restrict__ rs, const int* __restrict__ csr,
                                                 const float* __restrict__ dinv, const uint2* __restrict__ hp,
                                                 const float* __restrict__ bias, float* __restrict__ g, int n) {
    int wid = (blockIdx.x * 256 + threadIdx.x) >> 6;
    if (wid >= n) return;
    int lane = threadIdx.x & 63;
    int sub = lane >> 3;         // 0..7 edge subset
    int jl = lane & 7;           // uint2 index within 64B row
    int start = rs[wid], end = rs[wid + 1];
    float a0 = 0.f, a1 = 0.f, a2 = 0.f, a3 = 0.f;
    int i = start + sub;
    for (; i + 24 < end; i += 32) {
        int s0 = __builtin_nontemporal_load(csr + i);
        int s1 = __builtin_nontemporal_load(csr + i + 8);
        int s2 = __builtin_nontemporal_load(csr + i + 16);
        int s3 = __builtin_nontemporal_load(csr + i + 24);
        uint2 r0 = hp[((size_t)s0 << 3) + jl];
        uint2 r1 = hp[((size_t)s1 << 3) + jl];
        uint2 r2 = hp[((size_t)s2 << 3) + jl];
        uint2 r3 = hp[((size_t)s3 << 3) + jl];
        float2 p0 = __half22float2(*(__half2*)&r0.x), p1 = __half22float2(*(__half2*)&r0.y);
        float2 q0 = __half22float2(*(__half2*)&r1.x), q1 = __half22float2(*(__half2*)&r1.y);
        float2 u0 = __half22float2(*(__half2*)&r2.x), u1 = __half22float2(*(__half2*)&r2.y);
        float2 v0 = __half22float2(*(__half2*)&r3.x), v1 = __half22float2(*(__half2*)&r3.y);
        a0 += p0.x + q0.x + u0.x + v0.x;
        a1 += p0.y + q0.y + u0.y + v0.y;
        a2 += p1.x + q1.x + u1.x + v1.x;
        a3 += p1.y + q1.y + u1.y + v1.y;
    }
    for (; i < end; i += 8) {
        int s = __builtin_nontemporal_load(csr + i);
        uint2 r0 = hp[((size_t)s << 3) + jl];
        float2 p0 = __half22float2(*(__half2*)&r0.x), p1 = __half22float2(*(__half2*)&r0.y);
        a0 += p0.x; a1 += p0.y; a2 += p1.x; a3 += p1.y;
    }
    a0 += __shfl_xor(a0, 8);  a1 += __shfl_xor(a1, 8);
    a2 += __shfl_xor(a2, 8);  a3 += __shfl_xor(a3, 8);
    a0 += __shfl_xor(a0, 16); a1 += __shfl_xor(a1, 16);
    a2 += __shfl_xor(a2, 16); a3 += __shfl_xor(a3, 16);
    a0 += __shfl_xor(a0, 32); a1 += __shfl_xor(a1, 32);
    a2 += __shfl_xor(a2, 32); a3 += __shfl_xor(a3, 32);
    if (sub == 0) {
        float dv = dinv[wid];
        uint2 rs2 = hp[((size_t)wid << 3) + jl];
        float2 f0 = __half22float2(*(__half2*)&rs2.x), f1 = __half22float2(*(__half2*)&rs2.y);
        float4 bb = ((const float4*)bias)[jl];
        float4 r;
        r.x = dv * (a0 + f0.x) + bb.x;
        r.y = dv * (a1 + f0.y) + bb.y;
        r.z = dv * (a2 + f1.x) + bb.z;
        r.w = dv * (a3 + f1.y) + bb.w;
        r.x = r.x > 0.f ? r.x : expm1f(r.x);
        r.y = r.y > 0.f ? r.y : expm1f(r.y);
        r.z = r.z > 0.f ? r.z : expm1f(r.z);
        r.w = r.w > 0.f ? r.w : expm1f(r.w);
        ((float4*)(g + ((size_t)wid << 5)))[jl] = r;
    }
}

// ---- hw2 = fp16((g1 @ W2) * dinv)  (64 -> 32), single plane ----
__global__ __launch_bounds__(256) void k_gemm2(const float* __restrict__ g1, const float* __restrict__ W2,
                                               const float* __restrict__ dinv, __half* __restrict__ hw2, int n) {
    __shared__ float w[2048];
    __shared__ float xs[512];
    for (int i = threadIdx.x; i < 2048; i += 256) w[i] = W2[i];
    int nb = blockIdx.x * 8;
    for (int i = threadIdx.x; i < 512; i += 256) {
        int r = i >> 6, c = i & 63;
        int node = nb + r;
        xs[i] = (node < n) ? __builtin_nontemporal_load(g1 + (size_t)node * 64 + c) : 0.f;
    }
    __syncthreads();
    int node = nb + (threadIdx.x >> 5);
    int j = threadIdx.x & 31;
    if (node >= n) return;
    const float* xr = &xs[(threadIdx.x >> 5) << 6];
    float s = 0.f;
#pragma unroll
    for (int k = 0; k < 64; ++k) s += xr[k] * w[k * 32 + j];
    hw2[(size_t)node * 32 + j] = __float2half_rn(s * dinv[node]);
}

// ---- cooperative head: conv1d(32->16,k=3)+relu+fc(16->22), 64 rows/block, float4 ----
__global__ __launch_bounds__(256) void k_head(const float* __restrict__ g2, const float* __restrict__ cw,
                                              const float* __restrict__ cb, const float* __restrict__ fw,
                                              const float* __restrict__ fb, float* __restrict__ out,
                                              int nrows) {
    __shared__ float tile[(HROWS + 2) * 36];
    __shared__ float scwT[96 * 16];
    __shared__ float ytile[HROWS * 20];
    __shared__ float sfwT[22 * 16];
    __shared__ float scb[16], sfb[22];
    int base = blockIdx.x * HROWS;
    int rcnt = nrows - base; if (rcnt > HROWS) rcnt = HROWS;
    for (int i = threadIdx.x; i < 1536; i += 256) {
        int co = i / 96, rem = i - co * 96;
        scwT[rem * 16 + co] = cw[i];
    }
    for (int i = threadIdx.x; i < 352; i += 256) {
        int co = i / 22, col = i - co * 22;
        sfwT[col * 16 + co] = fw[i];
    }
    if (threadIdx.x < 16) scb[threadIdx.x] = cb[threadIdx.x];
    if (threadIdx.x < 22) sfb[threadIdx.x] = fb[threadIdx.x];
    int nload4 = (rcnt + 2) * 8;
    for (int i = threadIdx.x; i < nload4; i += 256) {
        int r = i >> 3, c4 = i & 7;
        float4 v = *(const float4*)(g2 + (size_t)(base + r) * 32 + c4 * 4);
        *(float4*)&tile[r * 36 + c4 * 4] = v;
    }
    __syncthreads();
    int r = threadIdx.x >> 2;
    int c0 = threadIdx.x & 3;
    if (r < rcnt) {
        float4 acc = { scb[c0 * 4], scb[c0 * 4 + 1], scb[c0 * 4 + 2], scb[c0 * 4 + 3] };
#pragma unroll
        for (int k = 0; k < 3; ++k) {
            const float* tr = &tile[(r + k) * 36];
#pragma unroll
            for (int ci4 = 0; ci4 < 8; ++ci4) {
                float4 xv = *(const float4*)&tr[ci4 * 4];
#pragma unroll
                for (int q = 0; q < 4; ++q) {
                    int ci = ci4 * 4 + q;
                    float4 wv = *(const float4*)&scwT[(ci * 3 + k) * 16 + c0 * 4];
                    float xq = q == 0 ? xv.x : q == 1 ? xv.y : q == 2 ? xv.z : xv.w;
                    acc.x += xq * wv.x;
                    acc.y += xq * wv.y;
                    acc.z += xq * wv.z;
                    acc.w += xq * wv.w;
                }
            }
        }
        float4 yv;
        yv.x = acc.x > 0.f ? acc.x : 0.f;
        yv.y = acc.y > 0.f ? acc.y : 0.f;
        yv.z = acc.z > 0.f ? acc.z : 0.f;
        yv.w = acc.w > 0.f ? acc.w : 0.f;
        *(float4*)&ytile[r * 20 + c0 * 4] = yv;
    }
    __syncthreads();
    int items = rcnt * 22;
    for (int it = threadIdx.x; it < items; it += 256) {
        int row = it / 22, col = it - row * 22;
        const float* yr = &ytile[row * 20];
        const float* wc = &sfwT[col * 16];
        float s = sfb[col];
#pragma unroll
        for (int co4 = 0; co4 < 4; ++co4) {
            float4 yv = *(const float4*)&yr[co4 * 4];
            float4 wv = *(const float4*)&wc[co4 * 4];
            s += yv.x * wv.x + yv.y * wv.y + yv.z * wv.z + yv.w * wv.w;
        }
        out[(size_t)base * 22 + it] = s;
    }
}

extern "C" void kernel_launch(void* const* d_in, const int* in_sizes, int n_in,
                              void* d_out, int out_size, void* d_ws, size_t ws_size,
                              hipStream_t stream) {
    const float* x  = (const float*)d_in[0];
    const int*   ei = (const int*)d_in[1];   // int32 (JAX x64 disabled)
    const float* W1 = (const float*)d_in[2];
    const float* b1 = (const float*)d_in[3];
    const float* W2 = (const float*)d_in[4];
    const float* b2 = (const float*)d_in[5];
    const float* cw = (const float*)d_in[6];
    const float* cb = (const float*)d_in[7];
    const float* fw = (const float*)d_in[8];
    const float* fb = (const float*)d_in[9];
    float* out = (float*)d_out;

    int N = in_sizes[0] / 8;       // 100000
    int E = in_sizes[1] / 2;       // 3200000
    const int* src = ei;
    const int* dst = ei + E;
    int NB = (N + BKT_NODES - 1) >> BKT_SHIFT;  // 391

    auto alignB = [](size_t v) { return (v + 1023) & ~(size_t)1023; };
    char* wsb = (char*)d_ws;
    size_t o = 0;
    int* bcnt = (int*)(wsb + o);      o += 2048;
    int* boff = (int*)(wsb + o);      o += 2048;
    int* bcur = (int*)(wsb + o);      o += 2048;
    int* rowstart = (int*)(wsb + o);  o += alignB((size_t)(N + 1) * 4);
    float* dinv = (float*)(wsb + o);  o += alignB((size_t)N * 4);
    int* csr = (int*)(wsb + o);       o += alignB((size_t)E * 4);
    __half2* hx = (__half2*)(wsb + o);  o += alignB((size_t)N * 8 * 2);   // [N][8] fp16
    __half* hw2 = (__half*)(wsb + o);   o += alignB((size_t)N * 32 * 2);  // [N][32] fp16
    float* B = (float*)(wsb + o);     o += (size_t)N * 64 * 4;            // g1, then g2
    int* ebuf = (int*)B;              // dead before B's first write

    hipMemsetAsync(bcnt, 0, (size_t)NB * sizeof(int), stream);
    k_hist<<<(E + 4095) / 4096, 256, 0, stream>>>(dst, bcnt, E, NB);
    k_bscan<<<1, 512, 0, stream>>>(bcnt, boff, bcur, NB, E);
    k_part<<<(E + 8191) / 8192, 256, 0, stream>>>(src, dst, bcur, ebuf, E, NB);
    k_lsort<<<NB, 256, 0, stream>>>(boff, ebuf, rowstart, dinv, csr, N, NB);

    k_hx<<<(N * 4 + 255) / 256, 256, 0, stream>>>(x, dinv, hx, N * 4);
    k_agg1v<<<(int)(((size_t)N * 64 + 255) / 256), 256, 0, stream>>>(rowstart, csr, dinv,
        (const uint2*)hx, W1, b1, B, N);

    k_gemm2<<<(N + 7) / 8, 256, 0, stream>>>(B, W2, dinv, hw2, N);
    k_aggr32v<<<(int)(((size_t)N * 64 + 255) / 256), 256, 0, stream>>>(rowstart, csr, dinv,
        (const uint2*)hw2, b2, B, N);

    k_head<<<(N - 2 + HROWS - 1) / HROWS, 256, 0, stream>>>(B, cw, cb, fw, fb, out, N - 2);
}

// Round 11
// 234.685 us; speedup vs baseline: 2.4420x; 1.1142x over previous
//
#include <hip/hip_runtime.h>
#include <hip/hip_fp16.h>
#include <math.h>

#define BKT_SHIFT 8
#define BKT_NODES 256
#define HROWS 64

// ---- pass 1: per-bucket histogram (int4-vectorized dst read) ----
__global__ __launch_bounds__(256) void k_hist(const int* __restrict__ dst,
                                              int* __restrict__ bcnt, int E, int NB) {
    __shared__ int lh[512];
    for (int i = threadIdx.x; i < NB; i += 256) lh[i] = 0;
    __syncthreads();
    int base = blockIdx.x * 4096;
    if (base + 4096 <= E) {
        const int4* d4 = (const int4*)(dst + base);
#pragma unroll
        for (int k = 0; k < 4; ++k) {
            int4 v = d4[k * 256 + threadIdx.x];
            atomicAdd(&lh[v.x >> BKT_SHIFT], 1);
            atomicAdd(&lh[v.y >> BKT_SHIFT], 1);
            atomicAdd(&lh[v.z >> BKT_SHIFT], 1);
            atomicAdd(&lh[v.w >> BKT_SHIFT], 1);
        }
    } else {
        for (int k = 0; k < 16; ++k) {
            int i = base + k * 256 + threadIdx.x;
            if (i < E) atomicAdd(&lh[dst[i] >> BKT_SHIFT], 1);
        }
    }
    __syncthreads();
    for (int i = threadIdx.x; i < NB; i += 256)
        if (lh[i]) atomicAdd(&bcnt[i], lh[i]);
}

// ---- exclusive scan over NB buckets (single block) ----
__global__ __launch_bounds__(512) void k_bscan(const int* __restrict__ bc,
                                               int* __restrict__ boff,
                                               int* __restrict__ bcur, int NB, int E) {
    __shared__ int s[512];
    __shared__ int carry;
    if (threadIdx.x == 0) carry = 0;
    __syncthreads();
    for (int base = 0; base < NB; base += 512) {
        int i = base + threadIdx.x;
        int v = (i < NB) ? bc[i] : 0;
        s[threadIdx.x] = v;
        __syncthreads();
        for (int off = 1; off < 512; off <<= 1) {
            int t = (threadIdx.x >= off) ? s[threadIdx.x - off] : 0;
            __syncthreads();
            s[threadIdx.x] += t;
            __syncthreads();
        }
        if (i < NB) {
            int ex = carry + s[threadIdx.x] - v;
            boff[i] = ex;
            bcur[i] = ex;
        }
        __syncthreads();
        if (threadIdx.x == 0) carry += s[511];
        __syncthreads();
    }
    if (threadIdx.x == 0) boff[NB] = E;
}

// ---- pass 2: partition edges; record = (d&255)<<24 | src ----
__global__ __launch_bounds__(256) void k_part(const int* __restrict__ src,
                                              const int* __restrict__ dst,
                                              int* __restrict__ bcur,
                                              int* __restrict__ ebuf, int E, int NB) {
    __shared__ int dstash[8192];
    __shared__ int lh[512];
    for (int i = threadIdx.x; i < NB; i += 256) lh[i] = 0;
    __syncthreads();
    int base = blockIdx.x * 8192;
    if (base + 8192 <= E) {
        const int4* d4 = (const int4*)(dst + base);
#pragma unroll
        for (int k = 0; k < 8; ++k) {
            int i4 = k * 256 + threadIdx.x;
            int4 v = d4[i4];
            *(int4*)&dstash[i4 * 4] = v;
            atomicAdd(&lh[v.x >> BKT_SHIFT], 1);
            atomicAdd(&lh[v.y >> BKT_SHIFT], 1);
            atomicAdd(&lh[v.z >> BKT_SHIFT], 1);
            atomicAdd(&lh[v.w >> BKT_SHIFT], 1);
        }
    } else {
        for (int k = 0; k < 32; ++k) {
            int idx = k * 256 + threadIdx.x;
            int i = base + idx;
            if (i < E) {
                int d = dst[i];
                dstash[idx] = d;
                atomicAdd(&lh[d >> BKT_SHIFT], 1);
            }
        }
    }
    __syncthreads();
    for (int t = threadIdx.x; t < NB; t += 256) {
        int c = lh[t];
        lh[t] = c ? atomicAdd(&bcur[t], c) : 0;
    }
    __syncthreads();
#pragma unroll
    for (int k = 0; k < 32; ++k) {
        int idx = k * 256 + threadIdx.x;
        int i = base + idx;
        if (i < E) {
            int d = dstash[idx];
            int pos = atomicAdd(&lh[d >> BKT_SHIFT], 1);
            ebuf[pos] = ((d & (BKT_NODES - 1)) << 24) | src[i];
        }
    }
}

// ---- pass 3: per-bucket counting sort -> csr (masked src), rowstart, dinv ----
__global__ __launch_bounds__(256) void k_lsort(const int* __restrict__ boff,
                                               const int* __restrict__ ebuf,
                                               int* __restrict__ rowstart,
                                               float* __restrict__ dinv,
                                               int* __restrict__ csr, int n, int NB) {
    __shared__ int off[256];
    __shared__ int cnt[256];
    int b = blockIdx.x;
    int start = boff[b], end = boff[b + 1];
    cnt[threadIdx.x] = 0;
    __syncthreads();
    for (int i = start + threadIdx.x; i < end; i += 256)
        atomicAdd(&cnt[((unsigned)ebuf[i]) >> 24], 1);
    __syncthreads();
    int v = cnt[threadIdx.x];
    off[threadIdx.x] = v;
    __syncthreads();
    for (int o = 1; o < 256; o <<= 1) {
        int t = (threadIdx.x >= o) ? off[threadIdx.x - o] : 0;
        __syncthreads();
        off[threadIdx.x] += t;
        __syncthreads();
    }
    int excl = off[threadIdx.x] - v;
    int node = (b << BKT_SHIFT) + threadIdx.x;
    if (node < n) {
        rowstart[node] = start + excl;
        dinv[node] = rsqrtf((float)v + 1.0f);  // +1 = self-loop
    }
    __syncthreads();
    off[threadIdx.x] = excl;  // reuse as cursor
    __syncthreads();
    for (int i = start + threadIdx.x; i < end; i += 256) {
        int rec = ebuf[i];
        int d = ((unsigned)rec) >> 24;
        int pos = atomicAdd(&off[d], 1);
        csr[start + pos] = rec & 0xFFFFFF;
    }
    if (b == NB - 1 && threadIdx.x == 0) rowstart[n] = end;
}

// ---- hx = fp16(x * dinv), [N][8] ----
__global__ __launch_bounds__(256) void k_hx(const float* __restrict__ x,
                                            const float* __restrict__ dinv,
                                            __half2* __restrict__ hx, int n4) {
    int t = blockIdx.x * 256 + threadIdx.x;
    if (t >= n4) return;
    float2 v = ((const float2*)x)[t];
    float dv = dinv[t >> 2];
    hx[t] = __floats2half2_rn(v.x * dv, v.y * dv);
}

// ---- fused layer-1: aggregate hx (8 feats) then @W1+bias+ELU (r6 version) ----
__global__ __launch_bounds__(256) void k_agg1f(const int* __restrict__ rs, const int* __restrict__ csr,
                                               const float* __restrict__ dinv, const __half2* __restrict__ hx,
                                               const float* __restrict__ W1, const float* __restrict__ bias,
                                               float* __restrict__ g, int n) {
    __shared__ float w[512];
    for (int i = threadIdx.x; i < 512; i += 256) w[i] = W1[i];
    __syncthreads();
    int wid = (blockIdx.x * 256 + threadIdx.x) >> 6;
    if (wid >= n) return;
    int lane = threadIdx.x & 63;
    int sub = lane >> 2;        // 0..15 edge subset
    int jp = lane & 3;          // half2 index
    int start = rs[wid], end = rs[wid + 1];
    float ax = 0.f, ay = 0.f;
    int i = start + sub;
    for (; i + 16 < end; i += 32) {
        int s0 = csr[i], s1 = csr[i + 16];
        float2 f0 = __half22float2(hx[((size_t)s0 << 2) + jp]);
        float2 f1 = __half22float2(hx[((size_t)s1 << 2) + jp]);
        ax += f0.x + f1.x;
        ay += f0.y + f1.y;
    }
    for (; i < end; i += 16) {
        float2 f = __half22float2(hx[((size_t)csr[i] << 2) + jp]);
        ax += f.x; ay += f.y;
    }
    if (sub == 0) {  // self-loop row
        float2 f = __half22float2(hx[((size_t)wid << 2) + jp]);
        ax += f.x; ay += f.y;
    }
#pragma unroll
    for (int m = 4; m < 64; m <<= 1) {
        ax += __shfl_xor(ax, m);
        ay += __shfl_xor(ay, m);
    }
    float dv = dinv[wid];
    float s = 0.f;
#pragma unroll
    for (int kp = 0; kp < 4; ++kp) {
        float a = __shfl(ax, kp);
        float b = __shfl(ay, kp);
        s += a * w[(2 * kp) * 64 + lane] + b * w[(2 * kp + 1) * 64 + lane];
    }
    float v = dv * s + bias[lane];
    g[(size_t)wid * 64 + lane] = v > 0.f ? v : expm1f(v);
}

// ---- layer-2 aggregation (r6/r7 champion): wave = 4 quarters x 16 lanes x half2 ----
__global__ __launch_bounds__(256) void k_aggr32h(const int* __restrict__ rs, const int* __restrict__ csr,
                                                 const float* __restrict__ dinv, const __half* __restrict__ hw,
                                                 const float* __restrict__ bias, float* __restrict__ g, int n) {
    int wid = (blockIdx.x * 256 + threadIdx.x) >> 6;
    if (wid >= n) return;
    int lane = threadIdx.x & 63;
    int q = lane >> 4;           // 0..3 : edge subset
    int j = lane & 15;           // feature pair index (feats 2j, 2j+1)
    int start = rs[wid], end = rs[wid + 1];
    const __half2* hp = (const __half2*)hw;
    float ax = 0.f, ay = 0.f;
    int i = start + q;
    for (; i + 12 < end; i += 16) {
        int s0 = csr[i], s1 = csr[i + 4], s2 = csr[i + 8], s3 = csr[i + 12];
        float2 f0 = __half22float2(hp[((size_t)s0 << 4) + j]);
        float2 f1 = __half22float2(hp[((size_t)s1 << 4) + j]);
        float2 f2 = __half22float2(hp[((size_t)s2 << 4) + j]);
        float2 f3 = __half22float2(hp[((size_t)s3 << 4) + j]);
        ax += f0.x + f1.x + f2.x + f3.x;
        ay += f0.y + f1.y + f2.y + f3.y;
    }
    for (; i < end; i += 4) {
        float2 f = __half22float2(hp[((size_t)csr[i] << 4) + j]);
        ax += f.x; ay += f.y;
    }
    ax += __shfl_xor(ax, 16);
    ay += __shfl_xor(ay, 16);
    ax += __shfl_xor(ax, 32);
    ay += __shfl_xor(ay, 32);
    if (q == 0) {
        float dv = dinv[wid];
        float2 fs = __half22float2(hp[((size_t)wid << 4) + j]);
        float2 bb = ((const float2*)bias)[j];
        float vx = dv * (ax + fs.x) + bb.x;
        float vy = dv * (ay + fs.y) + bb.y;
        float2 r;
        r.x = vx > 0.f ? vx : expm1f(vx);
        r.y = vy > 0.f ? vy : expm1f(vy);
        ((float2*)(g + ((size_t)wid << 5)))[j] = r;
    }
}

// ---- hw2 = fp16((g1 @ W2) * dinv)  (64 -> 32), single plane, plain loads ----
__global__ __launch_bounds__(256) void k_gemm2(const float* __restrict__ g1, const float* __restrict__ W2,
                                               const float* __restrict__ dinv, __half* __restrict__ hw2, int n) {
    __shared__ float w[2048];
    __shared__ float xs[512];
    for (int i = threadIdx.x; i < 2048; i += 256) w[i] = W2[i];
    int nb = blockIdx.x * 8;
    for (int i = threadIdx.x; i < 512; i += 256) {
        int r = i >> 6, c = i & 63;
        int node = nb + r;
        xs[i] = (node < n) ? g1[(size_t)node * 64 + c] : 0.f;
    }
    __syncthreads();
    int node = nb + (threadIdx.x >> 5);
    int j = threadIdx.x & 31;
    if (node >= n) return;
    const float* xr = &xs[(threadIdx.x >> 5) << 6];
    float s = 0.f;
#pragma unroll
    for (int k = 0; k < 64; ++k) s += xr[k] * w[k * 32 + j];
    hw2[(size_t)node * 32 + j] = __float2half_rn(s * dinv[node]);
}

// ---- cooperative head: conv1d(32->16,k=3)+relu+fc(16->22), 64 rows/block, float4 ----
__global__ __launch_bounds__(256) void k_head(const float* __restrict__ g2, const float* __restrict__ cw,
                                              const float* __restrict__ cb, const float* __restrict__ fw,
                                              const float* __restrict__ fb, float* __restrict__ out,
                                              int nrows) {
    __shared__ float tile[(HROWS + 2) * 36];
    __shared__ float scwT[96 * 16];
    __shared__ float ytile[HROWS * 20];
    __shared__ float sfwT[22 * 16];
    __shared__ float scb[16], sfb[22];
    int base = blockIdx.x * HROWS;
    int rcnt = nrows - base; if (rcnt > HROWS) rcnt = HROWS;
    for (int i = threadIdx.x; i < 1536; i += 256) {
        int co = i / 96, rem = i - co * 96;
        scwT[rem * 16 + co] = cw[i];
    }
    for (int i = threadIdx.x; i < 352; i += 256) {
        int co = i / 22, col = i - co * 22;
        sfwT[col * 16 + co] = fw[i];
    }
    if (threadIdx.x < 16) scb[threadIdx.x] = cb[threadIdx.x];
    if (threadIdx.x < 22) sfb[threadIdx.x] = fb[threadIdx.x];
    int nload4 = (rcnt + 2) * 8;
    for (int i = threadIdx.x; i < nload4; i += 256) {
        int r = i >> 3, c4 = i & 7;
        float4 v = *(const float4*)(g2 + (size_t)(base + r) * 32 + c4 * 4);
        *(float4*)&tile[r * 36 + c4 * 4] = v;
    }
    __syncthreads();
    int r = threadIdx.x >> 2;
    int c0 = threadIdx.x & 3;
    if (r < rcnt) {
        float4 acc = { scb[c0 * 4], scb[c0 * 4 + 1], scb[c0 * 4 + 2], scb[c0 * 4 + 3] };
#pragma unroll
        for (int k = 0; k < 3; ++k) {
            const float* tr = &tile[(r + k) * 36];
#pragma unroll
            for (int ci4 = 0; ci4 < 8; ++ci4) {
                float4 xv = *(const float4*)&tr[ci4 * 4];
#pragma unroll
                for (int q = 0; q < 4; ++q) {
                    int ci = ci4 * 4 + q;
                    float4 wv = *(const float4*)&scwT[(ci * 3 + k) * 16 + c0 * 4];
                    float xq = q == 0 ? xv.x : q == 1 ? xv.y : q == 2 ? xv.z : xv.w;
                    acc.x += xq * wv.x;
                    acc.y += xq * wv.y;
                    acc.z += xq * wv.z;
                    acc.w += xq * wv.w;
                }
            }
        }
        float4 yv;
        yv.x = acc.x > 0.f ? acc.x : 0.f;
        yv.y = acc.y > 0.f ? acc.y : 0.f;
        yv.z = acc.z > 0.f ? acc.z : 0.f;
        yv.w = acc.w > 0.f ? acc.w : 0.f;
        *(float4*)&ytile[r * 20 + c0 * 4] = yv;
    }
    __syncthreads();
    int items = rcnt * 22;
    for (int it = threadIdx.x; it < items; it += 256) {
        int row = it / 22, col = it - row * 22;
        const float* yr = &ytile[row * 20];
        const float* wc = &sfwT[col * 16];
        float s = sfb[col];
#pragma unroll
        for (int co4 = 0; co4 < 4; ++co4) {
            float4 yv = *(const float4*)&yr[co4 * 4];
            float4 wv = *(const float4*)&wc[co4 * 4];
            s += yv.x * wv.x + yv.y * wv.y + yv.z * wv.z + yv.w * wv.w;
        }
        out[(size_t)base * 22 + it] = s;
    }
}

extern "C" void kernel_launch(void* const* d_in, const int* in_sizes, int n_in,
                              void* d_out, int out_size, void* d_ws, size_t ws_size,
                              hipStream_t stream) {
    const float* x  = (const float*)d_in[0];
    const int*   ei = (const int*)d_in[1];   // int32 (JAX x64 disabled)
    const float* W1 = (const float*)d_in[2];
    const float* b1 = (const float*)d_in[3];
    const float* W2 = (const float*)d_in[4];
    const float* b2 = (const float*)d_in[5];
    const float* cw = (const float*)d_in[6];
    const float* cb = (const float*)d_in[7];
    const float* fw = (const float*)d_in[8];
    const float* fb = (const float*)d_in[9];
    float* out = (float*)d_out;

    int N = in_sizes[0] / 8;       // 100000
    int E = in_sizes[1] / 2;       // 3200000
    const int* src = ei;
    const int* dst = ei + E;
    int NB = (N + BKT_NODES - 1) >> BKT_SHIFT;  // 391

    auto alignB = [](size_t v) { return (v + 1023) & ~(size_t)1023; };
    char* wsb = (char*)d_ws;
    size_t o = 0;
    int* bcnt = (int*)(wsb + o);      o += 2048;
    int* boff = (int*)(wsb + o);      o += 2048;
    int* bcur = (int*)(wsb + o);      o += 2048;
    int* rowstart = (int*)(wsb + o);  o += alignB((size_t)(N + 1) * 4);
    float* dinv = (float*)(wsb + o);  o += alignB((size_t)N * 4);
    int* csr = (int*)(wsb + o);       o += alignB((size_t)E * 4);
    __half2* hx = (__half2*)(wsb + o);  o += alignB((size_t)N * 8 * 2);   // [N][8] fp16
    __half* hw2 = (__half*)(wsb + o);   o += alignB((size_t)N * 32 * 2);  // [N][32] fp16
    float* B = (float*)(wsb + o);     o += (size_t)N * 64 * 4;            // g1, then g2
    int* ebuf = (int*)B;              // dead before B's first write

    hipMemsetAsync(bcnt, 0, (size_t)NB * sizeof(int), stream);
    k_hist<<<(E + 4095) / 4096, 256, 0, stream>>>(dst, bcnt, E, NB);
    k_bscan<<<1, 512, 0, stream>>>(bcnt, boff, bcur, NB, E);
    k_part<<<(E + 8191) / 8192, 256, 0, stream>>>(src, dst, bcur, ebuf, E, NB);
    k_lsort<<<NB, 256, 0, stream>>>(boff, ebuf, rowstart, dinv, csr, N, NB);

    k_hx<<<(N * 4 + 255) / 256, 256, 0, stream>>>(x, dinv, hx, N * 4);
    k_agg1f<<<(int)(((size_t)N * 64 + 255) / 256), 256, 0, stream>>>(rowstart, csr, dinv, hx, W1, b1, B, N);

    k_gemm2<<<(N + 7) / 8, 256, 0, stream>>>(B, W2, dinv, hw2, N);
    k_aggr32h<<<(int)(((size_t)N * 64 + 255) / 256), 256, 0, stream>>>(rowstart, csr, dinv, hw2, b2, B, N);

    k_head<<<(N - 2 + HROWS - 1) / HROWS, 256, 0, stream>>>(B, cw, cb, fw, fb, out, N - 2);
}

// Round 12
// 220.473 us; speedup vs baseline: 2.5994x; 1.0645x over previous
//
#include <hip/hip_runtime.h>
#include <hip/hip_fp16.h>
#include <math.h>

#define BKT_SHIFT 8
#define BKT_NODES 256
#define HROWS 64

// ---- pass 1: per-bucket histogram (int4-vectorized dst read) ----
__global__ __launch_bounds__(256) void k_hist(const int* __restrict__ dst,
                                              int* __restrict__ bcnt, int E, int NB) {
    __shared__ int lh[512];
    for (int i = threadIdx.x; i < NB; i += 256) lh[i] = 0;
    __syncthreads();
    int base = blockIdx.x * 4096;
    if (base + 4096 <= E) {
        const int4* d4 = (const int4*)(dst + base);
#pragma unroll
        for (int k = 0; k < 4; ++k) {
            int4 v = d4[k * 256 + threadIdx.x];
            atomicAdd(&lh[v.x >> BKT_SHIFT], 1);
            atomicAdd(&lh[v.y >> BKT_SHIFT], 1);
            atomicAdd(&lh[v.z >> BKT_SHIFT], 1);
            atomicAdd(&lh[v.w >> BKT_SHIFT], 1);
        }
    } else {
        for (int k = 0; k < 16; ++k) {
            int i = base + k * 256 + threadIdx.x;
            if (i < E) atomicAdd(&lh[dst[i] >> BKT_SHIFT], 1);
        }
    }
    __syncthreads();
    for (int i = threadIdx.x; i < NB; i += 256)
        if (lh[i]) atomicAdd(&bcnt[i], lh[i]);
}

// ---- exclusive scan over NB buckets (single block) ----
__global__ __launch_bounds__(512) void k_bscan(const int* __restrict__ bc,
                                               int* __restrict__ boff,
                                               int* __restrict__ bcur, int NB, int E) {
    __shared__ int s[512];
    __shared__ int carry;
    if (threadIdx.x == 0) carry = 0;
    __syncthreads();
    for (int base = 0; base < NB; base += 512) {
        int i = base + threadIdx.x;
        int v = (i < NB) ? bc[i] : 0;
        s[threadIdx.x] = v;
        __syncthreads();
        for (int off = 1; off < 512; off <<= 1) {
            int t = (threadIdx.x >= off) ? s[threadIdx.x - off] : 0;
            __syncthreads();
            s[threadIdx.x] += t;
            __syncthreads();
        }
        if (i < NB) {
            int ex = carry + s[threadIdx.x] - v;
            boff[i] = ex;
            bcur[i] = ex;
        }
        __syncthreads();
        if (threadIdx.x == 0) carry += s[511];
        __syncthreads();
    }
    if (threadIdx.x == 0) boff[NB] = E;
}

// ---- pass 2: partition edges; record = (d&255)<<24 | src ----
__global__ __launch_bounds__(256) void k_part(const int* __restrict__ src,
                                              const int* __restrict__ dst,
                                              int* __restrict__ bcur,
                                              int* __restrict__ ebuf, int E, int NB) {
    __shared__ int dstash[8192];
    __shared__ int lh[512];
    for (int i = threadIdx.x; i < NB; i += 256) lh[i] = 0;
    __syncthreads();
    int base = blockIdx.x * 8192;
    if (base + 8192 <= E) {
        const int4* d4 = (const int4*)(dst + base);
#pragma unroll
        for (int k = 0; k < 8; ++k) {
            int i4 = k * 256 + threadIdx.x;
            int4 v = d4[i4];
            *(int4*)&dstash[i4 * 4] = v;
            atomicAdd(&lh[v.x >> BKT_SHIFT], 1);
            atomicAdd(&lh[v.y >> BKT_SHIFT], 1);
            atomicAdd(&lh[v.z >> BKT_SHIFT], 1);
            atomicAdd(&lh[v.w >> BKT_SHIFT], 1);
        }
    } else {
        for (int k = 0; k < 32; ++k) {
            int idx = k * 256 + threadIdx.x;
            int i = base + idx;
            if (i < E) {
                int d = dst[i];
                dstash[idx] = d;
                atomicAdd(&lh[d >> BKT_SHIFT], 1);
            }
        }
    }
    __syncthreads();
    for (int t = threadIdx.x; t < NB; t += 256) {
        int c = lh[t];
        lh[t] = c ? atomicAdd(&bcur[t], c) : 0;
    }
    __syncthreads();
#pragma unroll
    for (int k = 0; k < 32; ++k) {
        int idx = k * 256 + threadIdx.x;
        int i = base + idx;
        if (i < E) {
            int d = dstash[idx];
            int pos = atomicAdd(&lh[d >> BKT_SHIFT], 1);
            ebuf[pos] = ((d & (BKT_NODES - 1)) << 24) | src[i];
        }
    }
}

// ---- pass 3: per-bucket counting sort -> csr (masked src), rowstart, dinv ----
__global__ __launch_bounds__(256) void k_lsort(const int* __restrict__ boff,
                                               const int* __restrict__ ebuf,
                                               int* __restrict__ rowstart,
                                               float* __restrict__ dinv,
                                               int* __restrict__ csr, int n, int NB) {
    __shared__ int off[256];
    __shared__ int cnt[256];
    int b = blockIdx.x;
    int start = boff[b], end = boff[b + 1];
    cnt[threadIdx.x] = 0;
    __syncthreads();
    for (int i = start + threadIdx.x; i < end; i += 256)
        atomicAdd(&cnt[((unsigned)ebuf[i]) >> 24], 1);
    __syncthreads();
    int v = cnt[threadIdx.x];
    off[threadIdx.x] = v;
    __syncthreads();
    for (int o = 1; o < 256; o <<= 1) {
        int t = (threadIdx.x >= o) ? off[threadIdx.x - o] : 0;
        __syncthreads();
        off[threadIdx.x] += t;
        __syncthreads();
    }
    int excl = off[threadIdx.x] - v;
    int node = (b << BKT_SHIFT) + threadIdx.x;
    if (node < n) {
        rowstart[node] = start + excl;
        dinv[node] = rsqrtf((float)v + 1.0f);  // +1 = self-loop
    }
    __syncthreads();
    off[threadIdx.x] = excl;  // reuse as cursor
    __syncthreads();
    for (int i = start + threadIdx.x; i < end; i += 256) {
        int rec = ebuf[i];
        int d = ((unsigned)rec) >> 24;
        int pos = atomicAdd(&off[d], 1);
        csr[start + pos] = rec & 0xFFFFFF;
    }
    if (b == NB - 1 && threadIdx.x == 0) rowstart[n] = end;
}

// ---- hx = fp16(x * dinv), [N][8] ----
__global__ __launch_bounds__(256) void k_hx(const float* __restrict__ x,
                                            const float* __restrict__ dinv,
                                            __half2* __restrict__ hx, int n4) {
    int t = blockIdx.x * 256 + threadIdx.x;
    if (t >= n4) return;
    float2 v = ((const float2*)x)[t];
    float dv = dinv[t >> 2];
    hx[t] = __floats2half2_rn(v.x * dv, v.y * dv);
}

// ---- fused layer-1: aggregate hx (8 feats) then @W1+bias+ELU (r6 version) ----
__global__ __launch_bounds__(256) void k_agg1f(const int* __restrict__ rs, const int* __restrict__ csr,
                                               const float* __restrict__ dinv, const __half2* __restrict__ hx,
                                               const float* __restrict__ W1, const float* __restrict__ bias,
                                               float* __restrict__ g, int n) {
    __shared__ float w[512];
    for (int i = threadIdx.x; i < 512; i += 256) w[i] = W1[i];
    __syncthreads();
    int wid = (blockIdx.x * 256 + threadIdx.x) >> 6;
    if (wid >= n) return;
    int lane = threadIdx.x & 63;
    int sub = lane >> 2;        // 0..15 edge subset
    int jp = lane & 3;          // half2 index
    int start = rs[wid], end = rs[wid + 1];
    float ax = 0.f, ay = 0.f;
    int i = start + sub;
    for (; i + 16 < end; i += 32) {
        int s0 = csr[i], s1 = csr[i + 16];
        float2 f0 = __half22float2(hx[((size_t)s0 << 2) + jp]);
        float2 f1 = __half22float2(hx[((size_t)s1 << 2) + jp]);
        ax += f0.x + f1.x;
        ay += f0.y + f1.y;
    }
    for (; i < end; i += 16) {
        float2 f = __half22float2(hx[((size_t)csr[i] << 2) + jp]);
        ax += f.x; ay += f.y;
    }
    if (sub == 0) {  // self-loop row
        float2 f = __half22float2(hx[((size_t)wid << 2) + jp]);
        ax += f.x; ay += f.y;
    }
#pragma unroll
    for (int m = 4; m < 64; m <<= 1) {
        ax += __shfl_xor(ax, m);
        ay += __shfl_xor(ay, m);
    }
    float dv = dinv[wid];
    float s = 0.f;
#pragma unroll
    for (int kp = 0; kp < 4; ++kp) {
        float a = __shfl(ax, kp);
        float b = __shfl(ay, kp);
        s += a * w[(2 * kp) * 64 + lane] + b * w[(2 * kp + 1) * 64 + lane];
    }
    float v = dv * s + bias[lane];
    g[(size_t)wid * 64 + lane] = v > 0.f ? v : expm1f(v);
}

// ---- layer-2 aggregation: 4 nodes/wave, 16 lanes/node, unroll 8, no shuffles ----
__global__ __launch_bounds__(256) void k_aggr32x(const int* __restrict__ rs, const int* __restrict__ csr,
                                                 const float* __restrict__ dinv, const __half* __restrict__ hw,
                                                 const float* __restrict__ bias, float* __restrict__ g, int n) {
    int wid = (blockIdx.x * 256 + threadIdx.x) >> 4;
    if (wid >= n) return;
    int j = threadIdx.x & 15;           // feature pair (feats 2j, 2j+1)
    int start = rs[wid], end = rs[wid + 1];
    const __half2* hp = (const __half2*)hw;
    float ax = 0.f, ay = 0.f;
    int i = start;
    for (; i + 8 <= end; i += 8) {
        int s0 = csr[i],     s1 = csr[i + 1], s2 = csr[i + 2], s3 = csr[i + 3];
        int s4 = csr[i + 4], s5 = csr[i + 5], s6 = csr[i + 6], s7 = csr[i + 7];
        float2 f0 = __half22float2(hp[((size_t)s0 << 4) + j]);
        float2 f1 = __half22float2(hp[((size_t)s1 << 4) + j]);
        float2 f2 = __half22float2(hp[((size_t)s2 << 4) + j]);
        float2 f3 = __half22float2(hp[((size_t)s3 << 4) + j]);
        float2 f4 = __half22float2(hp[((size_t)s4 << 4) + j]);
        float2 f5 = __half22float2(hp[((size_t)s5 << 4) + j]);
        float2 f6 = __half22float2(hp[((size_t)s6 << 4) + j]);
        float2 f7 = __half22float2(hp[((size_t)s7 << 4) + j]);
        ax += f0.x + f1.x + f2.x + f3.x + f4.x + f5.x + f6.x + f7.x;
        ay += f0.y + f1.y + f2.y + f3.y + f4.y + f5.y + f6.y + f7.y;
    }
    for (; i < end; ++i) {
        int s = csr[i];
        float2 f = __half22float2(hp[((size_t)s << 4) + j]);
        ax += f.x; ay += f.y;
    }
    float dv = dinv[wid];
    float2 fs = __half22float2(hp[((size_t)wid << 4) + j]);
    float2 bb = ((const float2*)bias)[j];
    float vx = dv * (ax + fs.x) + bb.x;
    float vy = dv * (ay + fs.y) + bb.y;
    float2 r;
    r.x = vx > 0.f ? vx : expm1f(vx);
    r.y = vy > 0.f ? vy : expm1f(vy);
    ((float2*)(g + ((size_t)wid << 5)))[j] = r;
}

// ---- hw2 = fp16((g1 @ W2) * dinv)  (64 -> 32), single plane, plain loads ----
__global__ __launch_bounds__(256) void k_gemm2(const float* __restrict__ g1, const float* __restrict__ W2,
                                               const float* __restrict__ dinv, __half* __restrict__ hw2, int n) {
    __shared__ float w[2048];
    __shared__ float xs[512];
    for (int i = threadIdx.x; i < 2048; i += 256) w[i] = W2[i];
    int nb = blockIdx.x * 8;
    for (int i = threadIdx.x; i < 512; i += 256) {
        int r = i >> 6, c = i & 63;
        int node = nb + r;
        xs[i] = (node < n) ? g1[(size_t)node * 64 + c] : 0.f;
    }
    __syncthreads();
    int node = nb + (threadIdx.x >> 5);
    int j = threadIdx.x & 31;
    if (node >= n) return;
    const float* xr = &xs[(threadIdx.x >> 5) << 6];
    float s = 0.f;
#pragma unroll
    for (int k = 0; k < 64; ++k) s += xr[k] * w[k * 32 + j];
    hw2[(size_t)node * 32 + j] = __float2half_rn(s * dinv[node]);
}

// ---- cooperative head: conv1d(32->16,k=3)+relu+fc(16->22), 64 rows/block, float4 ----
__global__ __launch_bounds__(256) void k_head(const float* __restrict__ g2, const float* __restrict__ cw,
                                              const float* __restrict__ cb, const float* __restrict__ fw,
                                              const float* __restrict__ fb, float* __restrict__ out,
                                              int nrows) {
    __shared__ float tile[(HROWS + 2) * 36];
    __shared__ float scwT[96 * 16];
    __shared__ float ytile[HROWS * 20];
    __shared__ float sfwT[22 * 16];
    __shared__ float scb[16], sfb[22];
    int base = blockIdx.x * HROWS;
    int rcnt = nrows - base; if (rcnt > HROWS) rcnt = HROWS;
    for (int i = threadIdx.x; i < 1536; i += 256) {
        int co = i / 96, rem = i - co * 96;
        scwT[rem * 16 + co] = cw[i];
    }
    for (int i = threadIdx.x; i < 352; i += 256) {
        int co = i / 22, col = i - co * 22;
        sfwT[col * 16 + co] = fw[i];
    }
    if (threadIdx.x < 16) scb[threadIdx.x] = cb[threadIdx.x];
    if (threadIdx.x < 22) sfb[threadIdx.x] = fb[threadIdx.x];
    int nload4 = (rcnt + 2) * 8;
    for (int i = threadIdx.x; i < nload4; i += 256) {
        int r = i >> 3, c4 = i & 7;
        float4 v = *(const float4*)(g2 + (size_t)(base + r) * 32 + c4 * 4);
        *(float4*)&tile[r * 36 + c4 * 4] = v;
    }
    __syncthreads();
    int r = threadIdx.x >> 2;
    int c0 = threadIdx.x & 3;
    if (r < rcnt) {
        float4 acc = { scb[c0 * 4], scb[c0 * 4 + 1], scb[c0 * 4 + 2], scb[c0 * 4 + 3] };
#pragma unroll
        for (int k = 0; k < 3; ++k) {
            const float* tr = &tile[(r + k) * 36];
#pragma unroll
            for (int ci4 = 0; ci4 < 8; ++ci4) {
                float4 xv = *(const float4*)&tr[ci4 * 4];
#pragma unroll
                for (int q = 0; q < 4; ++q) {
                    int ci = ci4 * 4 + q;
                    float4 wv = *(const float4*)&scwT[(ci * 3 + k) * 16 + c0 * 4];
                    float xq = q == 0 ? xv.x : q == 1 ? xv.y : q == 2 ? xv.z : xv.w;
                    acc.x += xq * wv.x;
                    acc.y += xq * wv.y;
                    acc.z += xq * wv.z;
                    acc.w += xq * wv.w;
                }
            }
        }
        float4 yv;
        yv.x = acc.x > 0.f ? acc.x : 0.f;
        yv.y = acc.y > 0.f ? acc.y : 0.f;
        yv.z = acc.z > 0.f ? acc.z : 0.f;
        yv.w = acc.w > 0.f ? acc.w : 0.f;
        *(float4*)&ytile[r * 20 + c0 * 4] = yv;
    }
    __syncthreads();
    int items = rcnt * 22;
    for (int it = threadIdx.x; it < items; it += 256) {
        int row = it / 22, col = it - row * 22;
        const float* yr = &ytile[row * 20];
        const float* wc = &sfwT[col * 16];
        float s = sfb[col];
#pragma unroll
        for (int co4 = 0; co4 < 4; ++co4) {
            float4 yv = *(const float4*)&yr[co4 * 4];
            float4 wv = *(const float4*)&wc[co4 * 4];
            s += yv.x * wv.x + yv.y * wv.y + yv.z * wv.z + yv.w * wv.w;
        }
        out[(size_t)base * 22 + it] = s;
    }
}

extern "C" void kernel_launch(void* const* d_in, const int* in_sizes, int n_in,
                              void* d_out, int out_size, void* d_ws, size_t ws_size,
                              hipStream_t stream) {
    const float* x  = (const float*)d_in[0];
    const int*   ei = (const int*)d_in[1];   // int32 (JAX x64 disabled)
    const float* W1 = (const float*)d_in[2];
    const float* b1 = (const float*)d_in[3];
    const float* W2 = (const float*)d_in[4];
    const float* b2 = (const float*)d_in[5];
    const float* cw = (const float*)d_in[6];
    const float* cb = (const float*)d_in[7];
    const float* fw = (const float*)d_in[8];
    const float* fb = (const float*)d_in[9];
    float* out = (float*)d_out;

    int N = in_sizes[0] / 8;       // 100000
    int E = in_sizes[1] / 2;       // 3200000
    const int* src = ei;
    const int* dst = ei + E;
    int NB = (N + BKT_NODES - 1) >> BKT_SHIFT;  // 391

    auto alignB = [](size_t v) { return (v + 1023) & ~(size_t)1023; };
    char* wsb = (char*)d_ws;
    size_t o = 0;
    int* bcnt = (int*)(wsb + o);      o += 2048;
    int* boff = (int*)(wsb + o);      o += 2048;
    int* bcur = (int*)(wsb + o);      o += 2048;
    int* rowstart = (int*)(wsb + o);  o += alignB((size_t)(N + 1) * 4);
    float* dinv = (float*)(wsb + o);  o += alignB((size_t)N * 4);
    int* csr = (int*)(wsb + o);       o += alignB((size_t)E * 4);
    __half2* hx = (__half2*)(wsb + o);  o += alignB((size_t)N * 8 * 2);   // [N][8] fp16
    __half* hw2 = (__half*)(wsb + o);   o += alignB((size_t)N * 32 * 2);  // [N][32] fp16
    float* B = (float*)(wsb + o);     o += (size_t)N * 64 * 4;            // g1, then g2
    int* ebuf = (int*)B;              // dead before B's first write

    hipMemsetAsync(bcnt, 0, (size_t)NB * sizeof(int), stream);
    k_hist<<<(E + 4095) / 4096, 256, 0, stream>>>(dst, bcnt, E, NB);
    k_bscan<<<1, 512, 0, stream>>>(bcnt, boff, bcur, NB, E);
    k_part<<<(E + 8191) / 8192, 256, 0, stream>>>(src, dst, bcur, ebuf, E, NB);
    k_lsort<<<NB, 256, 0, stream>>>(boff, ebuf, rowstart, dinv, csr, N, NB);

    k_hx<<<(N * 4 + 255) / 256, 256, 0, stream>>>(x, dinv, hx, N * 4);
    k_agg1f<<<(int)(((size_t)N * 64 + 255) / 256), 256, 0, stream>>>(rowstart, csr, dinv, hx, W1, b1, B, N);

    k_gemm2<<<(N + 7) / 8, 256, 0, stream>>>(B, W2, dinv, hw2, N);
    k_aggr32x<<<(int)(((size_t)N * 16 + 255) / 256), 256, 0, stream>>>(rowstart, csr, dinv, hw2, b2, B, N);

    k_head<<<(N - 2 + HROWS - 1) / HROWS, 256, 0, stream>>>(B, cw, cb, fw, fb, out, N - 2);
}